// Round 7
// baseline (296.630 us; speedup 1.0000x reference)
//
#include <hip/hip_runtime.h>
#include <hip/hip_bf16.h>
#include <math.h>

typedef __bf16 bf16;
typedef __bf16 bf16x8 __attribute__((ext_vector_type(8)));
typedef __bf16 bf16x4 __attribute__((ext_vector_type(4)));
typedef float  f32x4  __attribute__((ext_vector_type(4)));
typedef int    i32x4  __attribute__((ext_vector_type(4)));

#define NB 2
#define NL 2048
#define NC 256
#define NH 8
#define NDK 32
#define JSPLIT 4
#define JCHUNK (NL / JSPLIT)   // 512
#define JTILES (JCHUNK / 64)   // 8
#define SCALE 0.17677669529663687f
#define NEGV  -4294967296.0f   // float32(-2^32+1) rounds to -2^32

// count-free pipeline fences (no hand vmcnt arithmetic anywhere):
#define DRAIN() do { \
    asm volatile("s_waitcnt vmcnt(0)" ::: "memory"); \
    __builtin_amdgcn_sched_barrier(0); } while (0)
#define LDSFENCE() do { \
    asm volatile("s_waitcnt lgkmcnt(0)" ::: "memory"); \
    __builtin_amdgcn_sched_barrier(0); } while (0)

// ---------------- fused QKV projection: [4096,256]@[256,256]+b -> bf16 ----------------
__global__ __launch_bounds__(256) void proj_kernel(
    const float* __restrict__ qx, const float* __restrict__ kx, const float* __restrict__ vx,
    const float* __restrict__ Wq, const float* __restrict__ bq,
    const float* __restrict__ Wk, const float* __restrict__ bk,
    const float* __restrict__ Wv, const float* __restrict__ bv,
    bf16* __restrict__ qo, bf16* __restrict__ ko, bf16* __restrict__ vto)
{
    const int mode = blockIdx.z;
    const float* X    = (mode == 0) ? qx : (mode == 1) ? kx : vx;
    const float* W    = (mode == 0) ? Wq : (mode == 1) ? Wk : Wv;
    const float* bias = (mode == 0) ? bq : (mode == 1) ? bk : bv;

    __shared__ float As[64][33];
    __shared__ float Bs[32][65];

    const int tid = threadIdx.x;
    const int tx = tid & 15, ty = tid >> 4;
    const int m0 = blockIdx.x * 64, n0 = blockIdx.y * 64;

    float acc[4][4] = {{0.f}};

    for (int k0 = 0; k0 < NC; k0 += 32) {
        const int ar = tid >> 2, ac = (tid & 3) << 3;
        const float4 a0 = *(const float4*)(X + (size_t)(m0 + ar) * NC + k0 + ac);
        const float4 a1 = *(const float4*)(X + (size_t)(m0 + ar) * NC + k0 + ac + 4);
        const int br = tid >> 3, bc = (tid & 7) << 3;
        const float4 b0 = *(const float4*)(W + (size_t)(k0 + br) * NC + n0 + bc);
        const float4 b1 = *(const float4*)(W + (size_t)(k0 + br) * NC + n0 + bc + 4);
        __syncthreads();
        As[ar][ac+0]=a0.x; As[ar][ac+1]=a0.y; As[ar][ac+2]=a0.z; As[ar][ac+3]=a0.w;
        As[ar][ac+4]=a1.x; As[ar][ac+5]=a1.y; As[ar][ac+6]=a1.z; As[ar][ac+7]=a1.w;
        Bs[br][bc+0]=b0.x; Bs[br][bc+1]=b0.y; Bs[br][bc+2]=b0.z; Bs[br][bc+3]=b0.w;
        Bs[br][bc+4]=b1.x; Bs[br][bc+5]=b1.y; Bs[br][bc+6]=b1.z; Bs[br][bc+7]=b1.w;
        __syncthreads();
        #pragma unroll
        for (int kk = 0; kk < 32; ++kk) {
            float av[4], bw[4];
            #pragma unroll
            for (int r = 0; r < 4; ++r) av[r] = As[ty*4+r][kk];
            #pragma unroll
            for (int c = 0; c < 4; ++c) bw[c] = Bs[kk][tx*4+c];
            #pragma unroll
            for (int r = 0; r < 4; ++r)
                #pragma unroll
                for (int c = 0; c < 4; ++c)
                    acc[r][c] = fmaf(av[r], bw[c], acc[r][c]);
        }
    }

    #pragma unroll
    for (int r = 0; r < 4; ++r) {
        const int row = m0 + ty*4 + r;
        const int bb_ = row >> 11, ll = row & (NL - 1);
        #pragma unroll
        for (int c = 0; c < 4; ++c) {
            const int col = n0 + tx*4 + c;
            const float v = acc[r][c] + bias[col];
            const int hh = col >> 5, d = col & 31;
            if (mode == 0)
                qo[(((size_t)bb_*NH + hh)*NL + ll)*NDK + d] = (bf16)v;
            else if (mode == 1)
                ko[(((size_t)bb_*NH + hh)*NL + ll)*NDK + d] = (bf16)v;
            else
                vto[(((size_t)bb_*NH + hh)*NDK + d)*NL + ll] = (bf16)v;
        }
    }
}

// -------- output GEMM with fused split-j combine: z = (Σ zp / Σ l) @ WO + b --------
__global__ __launch_bounds__(256) void out_gemm_kernel(
    const float* __restrict__ zp, const float* __restrict__ lbuf,
    const float* __restrict__ W, const float* __restrict__ bias,
    float* __restrict__ out)
{
    __shared__ float As[32][33];
    __shared__ float Bs[32][65];

    const int tid = threadIdx.x;
    const int tx = tid & 15, ty = tid >> 4;
    const int m0 = blockIdx.x * 32, n0 = blockIdx.y * 64;

    float acc[2][4] = {{0.f}};

    for (int k0 = 0; k0 < NC; k0 += 32) {
        const int hh = k0 >> 5;
        const int ar = tid >> 3, ac = (tid & 7) << 2;
        const int m = m0 + ar;
        const int bq_ = m >> 11, i = m & (NL - 1);
        const int bh = bq_ * NH + hh;
        // combine JSPLIT partials inline
        f32x4 a = {0.f, 0.f, 0.f, 0.f};
        float L = 0.f;
        #pragma unroll
        for (int js = 0; js < JSPLIT; ++js) {
            const size_t base = ((size_t)(bh * JSPLIT + js) * NL + i);
            a += *(const f32x4*)(zp + base * NDK + ac);
            L += lbuf[base];
        }
        const float rL = 1.0f / L;

        const int br = tid >> 3, bc = (tid & 7) << 3;
        const float4 b0 = *(const float4*)(W + (size_t)(k0 + br) * NC + n0 + bc);
        const float4 b1 = *(const float4*)(W + (size_t)(k0 + br) * NC + n0 + bc + 4);
        __syncthreads();
        As[ar][ac+0]=a[0]*rL; As[ar][ac+1]=a[1]*rL; As[ar][ac+2]=a[2]*rL; As[ar][ac+3]=a[3]*rL;
        Bs[br][bc+0]=b0.x; Bs[br][bc+1]=b0.y; Bs[br][bc+2]=b0.z; Bs[br][bc+3]=b0.w;
        Bs[br][bc+4]=b1.x; Bs[br][bc+5]=b1.y; Bs[br][bc+6]=b1.z; Bs[br][bc+7]=b1.w;
        __syncthreads();
        #pragma unroll
        for (int kk = 0; kk < 32; ++kk) {
            float av[2], bw[4];
            av[0] = As[ty*2+0][kk];
            av[1] = As[ty*2+1][kk];
            #pragma unroll
            for (int c = 0; c < 4; ++c) bw[c] = Bs[kk][tx*4+c];
            #pragma unroll
            for (int r = 0; r < 2; ++r)
                #pragma unroll
                for (int c = 0; c < 4; ++c)
                    acc[r][c] = fmaf(av[r], bw[c], acc[r][c]);
        }
    }

    #pragma unroll
    for (int r = 0; r < 2; ++r) {
        const int row = m0 + ty*2 + r;
        #pragma unroll
        for (int c = 0; c < 4; ++c) {
            const int col = n0 + tx*4 + c;
            out[(size_t)row * NC + col] = acc[r][c] + bias[col];
        }
    }
}

// ------- fused attention: fixed-max flash, count-free drain pipeline -------
// grid: (32*H, JSPLIT, B), block 256 = 4 independent waves (16 i-rows each).
// Per 64-j tile: issue {V(t),mask(t),K(t+1),pre(t+1)} plain loads, sched_barrier,
// compute tile t (K/pre guaranteed by previous DRAIN; V/mask by compiler's own
// counted waits), then DRAIN (vmcnt(0), count-independent, loads cannot cross it).
__global__ __launch_bounds__(256, 4) void attn_kernel(
    const bf16* __restrict__ q, const bf16* __restrict__ k, const bf16* __restrict__ vt,
    const float* __restrict__ preScores, const int* __restrict__ maskPAD,
    const float* __restrict__ embK, const float* __restrict__ embB,
    float* __restrict__ scores_out, float* __restrict__ zp, float* __restrict__ lbuf)
{
    const int h  = blockIdx.x & (NH - 1);
    const int i0 = (blockIdx.x >> 3) << 6;
    const int js = blockIdx.y;
    const int b  = blockIdx.z;
    const int tid = threadIdx.x;
    const int lane = tid & 63, w = tid >> 6;
    const int l15 = lane & 15, g = lane >> 4;

    __shared__ __align__(16) bf16 Ps[4][16][72];
    __shared__ float2 tab[16];

    if (tid < 15) tab[tid] = make_float2(embK[tid * NH + h], embB[tid * NH + h]);
    __syncthreads();

    const size_t bh = (size_t)b * NH + h;
    const int i_row = i0 + (w << 4) + l15;
    const bf16x8 bQ = *(const bf16x8*)(q + (bh * NL + i_row) * NDK + g * 8);

    const int jc0 = js * JCHUNK;
    const bf16*  kptr = k  + (bh * NL + jc0 + l15) * NDK + (g << 3);
    const bf16*  vptr = vt + (bh * NDK + l15) * NL + jc0 + (g << 3);
    const float* pptr = preScores + (bh * NL + i_row) * (size_t)NL + jc0 + (g << 2);
    const int*   mptr = maskPAD + ((size_t)b * NL + i_row) * (size_t)NL + jc0 + (g << 2);
    float* scoreRow = scores_out + (bh * NL + i_row) * (size_t)NL;

    uint4 kbuf[2][4]; f32x4 pbuf[2][4];

    // prologue: K(0), pre(0), then full drain
    #pragma unroll
    for (int tj = 0; tj < 4; ++tj)
        kbuf[0][tj] = *(const uint4*)(kptr + (size_t)tj * 16 * NDK);
    #pragma unroll
    for (int tj = 0; tj < 4; ++tj)
        pbuf[0][tj] = *(const f32x4*)(pptr + (tj << 4));
    DRAIN();

    f32x4 oF0 = {0.f, 0.f, 0.f, 0.f};
    f32x4 oF1 = {0.f, 0.f, 0.f, 0.f};
    const f32x4 zf = {0.f, 0.f, 0.f, 0.f};
    float l_lane = 0.f;

    #pragma unroll
    for (int jt = 0; jt < JTILES; ++jt) {
        const int j0  = jc0 + (jt << 6);
        const int cur = jt & 1, nxt = cur ^ 1;
        const bool more = (jt + 1 < JTILES);

        // issue V(t), mask(t) first (used this tile), then K(t+1), pre(t+1)
        uint4 vbuf[4]; i32x4 mbuf[4];
        vbuf[0] = *(const uint4*)(vptr + (jt << 6));
        vbuf[1] = *(const uint4*)(vptr + 16 * NL + (jt << 6));
        vbuf[2] = *(const uint4*)(vptr + (jt << 6) + 32);
        vbuf[3] = *(const uint4*)(vptr + 16 * NL + (jt << 6) + 32);
        #pragma unroll
        for (int tj = 0; tj < 4; ++tj)
            mbuf[tj] = *(const i32x4*)(mptr + (jt << 6) + (tj << 4));
        if (more) {
            #pragma unroll
            for (int tj = 0; tj < 4; ++tj)
                kbuf[nxt][tj] = *(const uint4*)(kptr + (size_t)(jt + 1) * 64 * NDK
                                                     + (size_t)tj * 16 * NDK);
            #pragma unroll
            for (int tj = 0; tj < 4; ++tj)
                pbuf[nxt][tj] = *(const f32x4*)(pptr + ((jt + 1) << 6) + (tj << 4));
        }
        __builtin_amdgcn_sched_barrier(0);   // pin issue burst above compute

        // per tj: QK^T mfma -> scores -> exp -> Ps  (sf kept to one f32x4)
        #pragma unroll
        for (int tj = 0; tj < 4; ++tj) {
            f32x4 sf = __builtin_amdgcn_mfma_f32_16x16x32_bf16(
                __builtin_bit_cast(bf16x8, kbuf[cur][tj]), bQ, zf, 0, 0, 0);
            const int jb = j0 + (tj << 4) + (g << 2);
            f32x4 out4; bf16x4 pk;
            #pragma unroll
            for (int r = 0; r < 4; ++r) {
                const int j = jb + r;
                int dd = i_row - j; dd = dd < 0 ? -dd : dd;
                int idx = dd;
                if (dd > 7) {
                    idx = 38 - __clz(dd - 7);   // 7 + floor(log2(dd-7)), exact
                    idx = idx > 14 ? 14 : idx;
                }
                const float2 kb2 = tab[idx];
                float sv = sf[r] * SCALE;
                sv = sv * kb2.x + kb2.y + pbuf[cur][tj][r];
                if (mbuf[tj][r] == 0) sv = NEGV;
                out4[r] = sv;
                const float e = __expf(sv);   // fixed-max: |sv| bounded, exp safe
                l_lane += e;
                pk[r] = (bf16)e;
            }
            *(f32x4*)(scoreRow + jb) = out4;
            *(bf16x4*)&Ps[w][l15][(tj << 4) | (g << 2)] = pk;
        }
        LDSFENCE();   // Ps writes visible to same wave before fragment reads

        // PV: Z += P * V  (vbuf arrival via compiler's counted wait)
        #pragma unroll
        for (int cc = 0; cc < 2; ++cc) {
            const bf16x8 aP = *(const bf16x8*)&Ps[w][l15][cc * 32 + g * 8];
            oF0 = __builtin_amdgcn_mfma_f32_16x16x32_bf16(
                aP, __builtin_bit_cast(bf16x8, vbuf[cc * 2 + 0]), oF0, 0, 0, 0);
            oF1 = __builtin_amdgcn_mfma_f32_16x16x32_bf16(
                aP, __builtin_bit_cast(bf16x8, vbuf[cc * 2 + 1]), oF1, 0, 0, 0);
        }

        DRAIN();   // K/pre(t+1) + this tile's stores all complete; count-free
    }

    // denominator: row i=l15 partials live in lanes {l15, l15+16, l15+32, l15+48}
    float lsum = l_lane;
    lsum += __shfl_xor(lsum, 16, 64);
    lsum += __shfl_xor(lsum, 32, 64);

    #pragma unroll
    for (int r = 0; r < 4; ++r) {
        const int i = i0 + (w << 4) + (g << 2) + r;
        float* zr = zp + ((bh * JSPLIT + js) * (size_t)NL + i) * NDK;
        zr[l15]      = oF0[r];
        zr[16 + l15] = oF1[r];
    }
    if (g == 0)
        lbuf[(bh * JSPLIT + js) * (size_t)NL + i_row] = lsum;
}

extern "C" void kernel_launch(void* const* d_in, const int* in_sizes, int n_in,
                              void* d_out, int out_size, void* d_ws, size_t ws_size,
                              hipStream_t stream) {
    (void)in_sizes; (void)n_in; (void)out_size; (void)ws_size;

    const float* qx        = (const float*)d_in[0];
    const float* kx        = (const float*)d_in[1];
    const float* vx        = (const float*)d_in[2];
    const float* preScores = (const float*)d_in[3];
    const int*   maskPAD   = (const int*)  d_in[4];
    const float* WQ_w      = (const float*)d_in[5];
    const float* WQ_b      = (const float*)d_in[6];
    const float* WK_w      = (const float*)d_in[7];
    const float* WK_b      = (const float*)d_in[8];
    const float* WV_w      = (const float*)d_in[9];
    const float* WV_b      = (const float*)d_in[10];
    const float* WO_w      = (const float*)d_in[11];
    const float* WO_b      = (const float*)d_in[12];
    const float* embK      = (const float*)d_in[13];
    const float* embB      = (const float*)d_in[14];

    char* ws = (char*)d_ws;
    bf16*  qb   = (bf16*)(ws);                    // 2 MB   [B,H,L,DK]
    bf16*  kb   = (bf16*)(ws + (2u << 20));       // 2 MB   [B,H,L,DK]
    bf16*  vtb  = (bf16*)(ws + (4u << 20));       // 2 MB   [B,H,DK,L]
    float* zpb  = (float*)(ws + (6u << 20));      // 16 MB  [B,H,JSPLIT,L,DK]
    float* lbuf = (float*)(ws + (22u << 20));     // 0.5 MB [B,H,JSPLIT,L]

    float* z_out      = (float*)d_out;                        // B*L*C
    float* scores_out = (float*)d_out + (size_t)NB * NL * NC; // B*H*L*L

    proj_kernel<<<dim3(64, 4, 3), 256, 0, stream>>>(
        qx, kx, vx, WQ_w, WQ_b, WK_w, WK_b, WV_w, WV_b, qb, kb, vtb);

    attn_kernel<<<dim3((NL / 64) * NH, JSPLIT, NB), 256, 0, stream>>>(
        qb, kb, vtb, preScores, maskPAD, embK, embB, scores_out, zpb, lbuf);

    out_gemm_kernel<<<dim3(NB * NL / 32, 4), 256, 0, stream>>>(zpb, lbuf, WO_w, WO_b, z_out);
}

// Round 8
// 245.108 us; speedup vs baseline: 1.2102x; 1.2102x over previous
//
#include <hip/hip_runtime.h>
#include <hip/hip_bf16.h>
#include <math.h>

typedef __bf16 bf16;
typedef __bf16 bf16x8 __attribute__((ext_vector_type(8)));
typedef __bf16 bf16x4 __attribute__((ext_vector_type(4)));
typedef float  f32x4  __attribute__((ext_vector_type(4)));
typedef int    i32x4  __attribute__((ext_vector_type(4)));

#define NB 2
#define NL 2048
#define NC 256
#define NH 8
#define NDK 32
#define JSPLIT 4
#define JCHUNK (NL / JSPLIT)   // 512
#define JTILES (JCHUNK / 64)   // 8
#define SCALE 0.17677669529663687f
#define NEGV  -4294967296.0f   // float32(-2^32+1) rounds to -2^32

#define PIN() __builtin_amdgcn_sched_barrier(0)
#define LDSFENCE() do { \
    asm volatile("s_waitcnt lgkmcnt(0)" ::: "memory"); \
    __builtin_amdgcn_sched_barrier(0); } while (0)

// ---------------- fused QKV projection: [4096,256]@[256,256]+b -> bf16 ----------------
__global__ __launch_bounds__(256) void proj_kernel(
    const float* __restrict__ qx, const float* __restrict__ kx, const float* __restrict__ vx,
    const float* __restrict__ Wq, const float* __restrict__ bq,
    const float* __restrict__ Wk, const float* __restrict__ bk,
    const float* __restrict__ Wv, const float* __restrict__ bv,
    bf16* __restrict__ qo, bf16* __restrict__ ko, bf16* __restrict__ vto)
{
    const int mode = blockIdx.z;
    const float* X    = (mode == 0) ? qx : (mode == 1) ? kx : vx;
    const float* W    = (mode == 0) ? Wq : (mode == 1) ? Wk : Wv;
    const float* bias = (mode == 0) ? bq : (mode == 1) ? bk : bv;

    __shared__ float As[64][33];
    __shared__ float Bs[32][65];

    const int tid = threadIdx.x;
    const int tx = tid & 15, ty = tid >> 4;
    const int m0 = blockIdx.x * 64, n0 = blockIdx.y * 64;

    float acc[4][4] = {{0.f}};

    for (int k0 = 0; k0 < NC; k0 += 32) {
        const int ar = tid >> 2, ac = (tid & 3) << 3;
        const float4 a0 = *(const float4*)(X + (size_t)(m0 + ar) * NC + k0 + ac);
        const float4 a1 = *(const float4*)(X + (size_t)(m0 + ar) * NC + k0 + ac + 4);
        const int br = tid >> 3, bc = (tid & 7) << 3;
        const float4 b0 = *(const float4*)(W + (size_t)(k0 + br) * NC + n0 + bc);
        const float4 b1 = *(const float4*)(W + (size_t)(k0 + br) * NC + n0 + bc + 4);
        __syncthreads();
        As[ar][ac+0]=a0.x; As[ar][ac+1]=a0.y; As[ar][ac+2]=a0.z; As[ar][ac+3]=a0.w;
        As[ar][ac+4]=a1.x; As[ar][ac+5]=a1.y; As[ar][ac+6]=a1.z; As[ar][ac+7]=a1.w;
        Bs[br][bc+0]=b0.x; Bs[br][bc+1]=b0.y; Bs[br][bc+2]=b0.z; Bs[br][bc+3]=b0.w;
        Bs[br][bc+4]=b1.x; Bs[br][bc+5]=b1.y; Bs[br][bc+6]=b1.z; Bs[br][bc+7]=b1.w;
        __syncthreads();
        #pragma unroll
        for (int kk = 0; kk < 32; ++kk) {
            float av[4], bw[4];
            #pragma unroll
            for (int r = 0; r < 4; ++r) av[r] = As[ty*4+r][kk];
            #pragma unroll
            for (int c = 0; c < 4; ++c) bw[c] = Bs[kk][tx*4+c];
            #pragma unroll
            for (int r = 0; r < 4; ++r)
                #pragma unroll
                for (int c = 0; c < 4; ++c)
                    acc[r][c] = fmaf(av[r], bw[c], acc[r][c]);
        }
    }

    #pragma unroll
    for (int r = 0; r < 4; ++r) {
        const int row = m0 + ty*4 + r;
        const int bb_ = row >> 11, ll = row & (NL - 1);
        #pragma unroll
        for (int c = 0; c < 4; ++c) {
            const int col = n0 + tx*4 + c;
            const float v = acc[r][c] + bias[col];
            const int hh = col >> 5, d = col & 31;
            if (mode == 0)
                qo[(((size_t)bb_*NH + hh)*NL + ll)*NDK + d] = (bf16)v;
            else if (mode == 1)
                ko[(((size_t)bb_*NH + hh)*NL + ll)*NDK + d] = (bf16)v;
            else
                vto[(((size_t)bb_*NH + hh)*NDK + d)*NL + ll] = (bf16)v;
        }
    }
}

// -------- output GEMM with fused split-j combine: z = (Σ zp / Σ l) @ WO + b --------
__global__ __launch_bounds__(256) void out_gemm_kernel(
    const float* __restrict__ zp, const float* __restrict__ lbuf,
    const float* __restrict__ W, const float* __restrict__ bias,
    float* __restrict__ out)
{
    __shared__ float As[32][33];
    __shared__ float Bs[32][65];

    const int tid = threadIdx.x;
    const int tx = tid & 15, ty = tid >> 4;
    const int m0 = blockIdx.x * 32, n0 = blockIdx.y * 64;

    float acc[2][4] = {{0.f}};

    for (int k0 = 0; k0 < NC; k0 += 32) {
        const int hh = k0 >> 5;
        const int ar = tid >> 3, ac = (tid & 7) << 2;
        const int m = m0 + ar;
        const int bq_ = m >> 11, i = m & (NL - 1);
        const int bh = bq_ * NH + hh;
        // combine JSPLIT partials inline
        f32x4 a = {0.f, 0.f, 0.f, 0.f};
        float L = 0.f;
        #pragma unroll
        for (int js = 0; js < JSPLIT; ++js) {
            const size_t base = ((size_t)(bh * JSPLIT + js) * NL + i);
            a += *(const f32x4*)(zp + base * NDK + ac);
            L += lbuf[base];
        }
        const float rL = 1.0f / L;

        const int br = tid >> 3, bc = (tid & 7) << 3;
        const float4 b0 = *(const float4*)(W + (size_t)(k0 + br) * NC + n0 + bc);
        const float4 b1 = *(const float4*)(W + (size_t)(k0 + br) * NC + n0 + bc + 4);
        __syncthreads();
        As[ar][ac+0]=a[0]*rL; As[ar][ac+1]=a[1]*rL; As[ar][ac+2]=a[2]*rL; As[ar][ac+3]=a[3]*rL;
        Bs[br][bc+0]=b0.x; Bs[br][bc+1]=b0.y; Bs[br][bc+2]=b0.z; Bs[br][bc+3]=b0.w;
        Bs[br][bc+4]=b1.x; Bs[br][bc+5]=b1.y; Bs[br][bc+6]=b1.z; Bs[br][bc+7]=b1.w;
        __syncthreads();
        #pragma unroll
        for (int kk = 0; kk < 32; ++kk) {
            float av[2], bw[4];
            av[0] = As[ty*2+0][kk];
            av[1] = As[ty*2+1][kk];
            #pragma unroll
            for (int c = 0; c < 4; ++c) bw[c] = Bs[kk][tx*4+c];
            #pragma unroll
            for (int r = 0; r < 2; ++r)
                #pragma unroll
                for (int c = 0; c < 4; ++c)
                    acc[r][c] = fmaf(av[r], bw[c], acc[r][c]);
        }
    }

    #pragma unroll
    for (int r = 0; r < 2; ++r) {
        const int row = m0 + ty*2 + r;
        #pragma unroll
        for (int c = 0; c < 4; ++c) {
            const int col = n0 + tx*4 + c;
            out[(size_t)row * NC + col] = acc[r][c] + bias[col];
        }
    }
}

// ------- fused attention: fixed-max flash, staggered-issue pipeline -------
// grid: (32*H, JSPLIT, B), block 256 = 4 independent waves (16 i-rows each).
// waves_per_eu(4,4): hard 128-VGPR budget so staged loads neither sink (R4)
// nor spill (R7). Issue points staggered so buffer live-ranges don't overlap:
//   QK(K_t) | issue K(t+1) | scores(pre_t,mask_t) | issue pre/mask(t+1) |
//   exp/pack | PV(V_t) | issue V(t+1)
__global__ __launch_bounds__(256) __attribute__((amdgpu_waves_per_eu(4, 4)))
void attn_kernel(
    const bf16* __restrict__ q, const bf16* __restrict__ k, const bf16* __restrict__ vt,
    const float* __restrict__ preScores, const int* __restrict__ maskPAD,
    const float* __restrict__ embK, const float* __restrict__ embB,
    float* __restrict__ scores_out, float* __restrict__ zp, float* __restrict__ lbuf)
{
    const int h  = blockIdx.x & (NH - 1);
    const int i0 = (blockIdx.x >> 3) << 6;
    const int js = blockIdx.y;
    const int b  = blockIdx.z;
    const int tid = threadIdx.x;
    const int lane = tid & 63, w = tid >> 6;
    const int l15 = lane & 15, g = lane >> 4;

    __shared__ __align__(16) bf16 Ps[4][16][72];
    __shared__ float2 tab[16];

    if (tid < 15) tab[tid] = make_float2(embK[tid * NH + h], embB[tid * NH + h]);
    __syncthreads();

    const size_t bh = (size_t)b * NH + h;
    const int i_row = i0 + (w << 4) + l15;
    const bf16x8 bQ = *(const bf16x8*)(q + (bh * NL + i_row) * NDK + g * 8);

    const int jc0 = js * JCHUNK;
    const bf16*  kptr  = k  + (bh * NL + jc0 + l15) * NDK + (g << 3);
    const bf16*  vptr  = vt + (bh * NDK + l15) * NL + jc0 + (g << 3);
    const bf16*  vptr2 = vptr + 16 * NL;
    const float* pptr  = preScores + (bh * NL + i_row) * (size_t)NL + jc0 + (g << 2);
    const int*   mptr  = maskPAD + ((size_t)b * NL + i_row) * (size_t)NL + jc0 + (g << 2);
    float* scoreRow = scores_out + (bh * NL + i_row) * (size_t)NL;

    uint4 kbuf[4], vbuf[4]; f32x4 pbuf[4]; i32x4 mbuf[4];

    // prologue: all of tile 0 (K first — needed first)
    #pragma unroll
    for (int tj = 0; tj < 4; ++tj)
        kbuf[tj] = *(const uint4*)(kptr + (size_t)tj * 16 * NDK);
    #pragma unroll
    for (int tj = 0; tj < 4; ++tj)
        pbuf[tj] = __builtin_nontemporal_load((const f32x4*)(pptr + (tj << 4)));
    #pragma unroll
    for (int tj = 0; tj < 4; ++tj)
        mbuf[tj] = *(const i32x4*)(mptr + (tj << 4));
    vbuf[0] = *(const uint4*)(vptr);
    vbuf[1] = *(const uint4*)(vptr2);
    vbuf[2] = *(const uint4*)(vptr + 32);
    vbuf[3] = *(const uint4*)(vptr2 + 32);
    PIN();

    f32x4 oF0 = {0.f, 0.f, 0.f, 0.f};
    f32x4 oF1 = {0.f, 0.f, 0.f, 0.f};
    const f32x4 zf = {0.f, 0.f, 0.f, 0.f};
    float l_lane = 0.f;

    #pragma unroll
    for (int jt = 0; jt < JTILES; ++jt) {
        const int j0 = jc0 + (jt << 6);
        const bool more = (jt + 1 < JTILES);

        // A: QK^T MFMAs (compiler's counted wait covers kbuf arrival)
        f32x4 sf[4];
        #pragma unroll
        for (int tj = 0; tj < 4; ++tj)
            sf[tj] = __builtin_amdgcn_mfma_f32_16x16x32_bf16(
                __builtin_bit_cast(bf16x8, kbuf[tj]), bQ, zf, 0, 0, 0);

        // B: kbuf dead -> issue K(t+1) into same names (regs reusable)
        if (more) {
            #pragma unroll
            for (int tj = 0; tj < 4; ++tj)
                kbuf[tj] = *(const uint4*)(kptr + (size_t)(jt + 1) * 64 * NDK
                                                + (size_t)tj * 16 * NDK);
            PIN();
        }

        // C: scores = S*kb + bb + pre, mask, store, exp, pack -> Ps
        #pragma unroll
        for (int tj = 0; tj < 4; ++tj) {
            const int jb = j0 + (tj << 4) + (g << 2);
            f32x4 out4; bf16x4 pk;
            #pragma unroll
            for (int r = 0; r < 4; ++r) {
                const int j = jb + r;
                int dd = i_row - j; dd = dd < 0 ? -dd : dd;
                int idx = dd;
                if (dd > 7) {
                    idx = 38 - __clz(dd - 7);   // 7 + floor(log2(dd-7)), exact
                    idx = idx > 14 ? 14 : idx;
                }
                const float2 kb2 = tab[idx];
                float sv = sf[tj][r] * SCALE;
                sv = sv * kb2.x + kb2.y + pbuf[tj][r];
                if (mbuf[tj][r] == 0) sv = NEGV;
                out4[r] = sv;
                const float e = __expf(sv);   // fixed-max: |sv| bounded (~±11)
                l_lane += e;
                pk[r] = (bf16)e;
            }
            *(f32x4*)(scoreRow + jb) = out4;
            *(bf16x4*)&Ps[w][l15][(tj << 4) | (g << 2)] = pk;
        }

        // D: pbuf/mbuf dead -> issue pre/mask(t+1)
        if (more) {
            #pragma unroll
            for (int tj = 0; tj < 4; ++tj)
                pbuf[tj] = __builtin_nontemporal_load(
                    (const f32x4*)(pptr + ((jt + 1) << 6) + (tj << 4)));
            #pragma unroll
            for (int tj = 0; tj < 4; ++tj)
                mbuf[tj] = *(const i32x4*)(mptr + ((jt + 1) << 6) + (tj << 4));
            PIN();
        }

        LDSFENCE();   // Ps writes visible to same wave before fragment reads

        // F: PV consumes vbuf (compiler's counted wait covers arrival)
        #pragma unroll
        for (int cc = 0; cc < 2; ++cc) {
            const bf16x8 aP = *(const bf16x8*)&Ps[w][l15][cc * 32 + g * 8];
            oF0 = __builtin_amdgcn_mfma_f32_16x16x32_bf16(
                aP, __builtin_bit_cast(bf16x8, vbuf[cc * 2 + 0]), oF0, 0, 0, 0);
            oF1 = __builtin_amdgcn_mfma_f32_16x16x32_bf16(
                aP, __builtin_bit_cast(bf16x8, vbuf[cc * 2 + 1]), oF1, 0, 0, 0);
        }

        // G: vbuf dead -> issue V(t+1)
        if (more) {
            vbuf[0] = *(const uint4*)(vptr + ((jt + 1) << 6));
            vbuf[1] = *(const uint4*)(vptr2 + ((jt + 1) << 6));
            vbuf[2] = *(const uint4*)(vptr + ((jt + 1) << 6) + 32);
            vbuf[3] = *(const uint4*)(vptr2 + ((jt + 1) << 6) + 32);
            PIN();
        }
    }

    // denominator: row i=l15 partials live in lanes {l15, l15+16, l15+32, l15+48}
    float lsum = l_lane;
    lsum += __shfl_xor(lsum, 16, 64);
    lsum += __shfl_xor(lsum, 32, 64);

    #pragma unroll
    for (int r = 0; r < 4; ++r) {
        const int i = i0 + (w << 4) + (g << 2) + r;
        float* zr = zp + ((bh * JSPLIT + js) * (size_t)NL + i) * NDK;
        zr[l15]      = oF0[r];
        zr[16 + l15] = oF1[r];
    }
    if (g == 0)
        lbuf[(bh * JSPLIT + js) * (size_t)NL + i_row] = lsum;
}

extern "C" void kernel_launch(void* const* d_in, const int* in_sizes, int n_in,
                              void* d_out, int out_size, void* d_ws, size_t ws_size,
                              hipStream_t stream) {
    (void)in_sizes; (void)n_in; (void)out_size; (void)ws_size;

    const float* qx        = (const float*)d_in[0];
    const float* kx        = (const float*)d_in[1];
    const float* vx        = (const float*)d_in[2];
    const float* preScores = (const float*)d_in[3];
    const int*   maskPAD   = (const int*)  d_in[4];
    const float* WQ_w      = (const float*)d_in[5];
    const float* WQ_b      = (const float*)d_in[6];
    const float* WK_w      = (const float*)d_in[7];
    const float* WK_b      = (const float*)d_in[8];
    const float* WV_w      = (const float*)d_in[9];
    const float* WV_b      = (const float*)d_in[10];
    const float* WO_w      = (const float*)d_in[11];
    const float* WO_b      = (const float*)d_in[12];
    const float* embK      = (const float*)d_in[13];
    const float* embB      = (const float*)d_in[14];

    char* ws = (char*)d_ws;
    bf16*  qb   = (bf16*)(ws);                    // 2 MB   [B,H,L,DK]
    bf16*  kb   = (bf16*)(ws + (2u << 20));       // 2 MB   [B,H,L,DK]
    bf16*  vtb  = (bf16*)(ws + (4u << 20));       // 2 MB   [B,H,DK,L]
    float* zpb  = (float*)(ws + (6u << 20));      // 16 MB  [B,H,JSPLIT,L,DK]
    float* lbuf = (float*)(ws + (22u << 20));     // 0.5 MB [B,H,JSPLIT,L]

    float* z_out      = (float*)d_out;                        // B*L*C
    float* scores_out = (float*)d_out + (size_t)NB * NL * NC; // B*H*L*L

    proj_kernel<<<dim3(64, 4, 3), 256, 0, stream>>>(
        qx, kx, vx, WQ_w, WQ_b, WK_w, WK_b, WV_w, WV_b, qb, kb, vtb);

    attn_kernel<<<dim3((NL / 64) * NH, JSPLIT, NB), 256, 0, stream>>>(
        qb, kb, vtb, preScores, maskPAD, embK, embB, scores_out, zpb, lbuf);

    out_gemm_kernel<<<dim3(NB * NL / 32, 4), 256, 0, stream>>>(zpb, lbuf, WO_w, WO_b, z_out);
}